// Round 18
// baseline (972.925 us; speedup 1.0000x reference)
//
#include <hip/hip_runtime.h>

// BiLSTM-CRF on MI355X. Round 18: fix K2 LDS-epilogue coverage bug (round 17
// wrote only half the gi columns): chunks are now c8*8 for c8 in [0,16).
// Everything else identical to round 17 (conv ch-dedup kept).

#define DEV __device__ __forceinline__
typedef unsigned short u16;
typedef unsigned int   u32;
typedef unsigned char  u8;
typedef signed char    s8;
using short8  = __attribute__((ext_vector_type(8))) short;
using f32x4   = __attribute__((ext_vector_type(4))) float;
using int4v   = __attribute__((ext_vector_type(4))) int;

DEV float bf2f(u16 u){ union{u32 i; float f;} v; v.i = ((u32)u)<<16; return v.f; }
DEV u16 f2bf(float f){ u32 x = __float_as_uint(f); return (u16)((x + 0x7fffu + ((x>>16)&1u)) >> 16); }
DEV u32 pk2(float a, float b){ return (u32)f2bf(a) | ((u32)f2bf(b) << 16); }
DEV float sigf(float x){ return __builtin_amdgcn_rcpf(1.f + __expf(-x)); }
DEV float tanh_f(float x){ return 1.f - 2.f*__builtin_amdgcn_rcpf(__expf(2.f*x) + 1.f); }
DEV float rdlane_f(float v, int l){
  return __uint_as_float(__builtin_amdgcn_readlane(__float_as_uint(v), l));
}

typedef __attribute__((address_space(1))) const u32 GU;
typedef __attribute__((address_space(3))) u32 LU;
DEV void gld_lds16(const void* g, void* l){
  __builtin_amdgcn_global_load_lds((GU*)g, (LU*)l, 16, 0, 0);
}
DEV void bar_l(){
  __builtin_amdgcn_sched_barrier(0);
  asm volatile("s_waitcnt lgkmcnt(0)" ::: "memory");
  __builtin_amdgcn_s_barrier();
  __builtin_amdgcn_sched_barrier(0);
}

// ---------------- ws layout (aliased; total ~170MB) ----------------
static const size_t OFF_GI   = 0;
static const size_t OFF_P    = 0;
static const size_t OFF_DL   = OFF_P  + (size_t)32768*16*4;
static const size_t OFF_PSI  = OFF_DL + (size_t)32768*16*4;
static const size_t OFF_B    = (size_t)134217728;
static const size_t OFF_WIH  = OFF_B    + (size_t)33554432;
static const size_t OFF_WQ   = OFF_WIH  + (size_t)1703936;   // 512KB i8 frags
static const size_t OFF_SC   = OFF_WQ   + (size_t)524288;    // 8KB scales
static const size_t OFF_BIAS = OFF_SC   + 8192;
static const size_t OFF_WFC  = OFF_BIAS + 8192;
static const size_t REQUIRED = OFF_WFC  + 256;

// LDS byte-offset helpers (XOR swizzle within 128B-multiple row strides)
#define CEB(r, byo) ((r)*128 + ((byo) ^ (((r)&7)<<4)))
#define WBB(r, byo) (33024 + (r)*384 + ((byo) ^ (((r)&7)<<4)))

// ---------------- K01: fused conv-GEMM / feat-copy / k0 ----------------
__global__ __launch_bounds__(256) void k01_fused(
    const int* __restrict__ X, const int* __restrict__ tg, const int* __restrict__ ch,
    const float* __restrict__ etab, const float* __restrict__ ttab, const float* __restrict__ ctab,
    const float* __restrict__ cw, const float* __restrict__ cb, u16* __restrict__ feat,
    const float* __restrict__ whhf, const float* __restrict__ whhb,
    s8* __restrict__ wq, float* __restrict__ sc2,
    const float* bihf, const float* bhhf, const float* bihb, const float* bhhb,
    const float* fcw, const float* wdp, float* bias, float* wfc,
    const float* __restrict__ wihf, const float* __restrict__ wihb, u16* __restrict__ wih)
{
  __shared__ float smemf[14400];   // 57600B: ce rows [258][128B] | B [64][384B]
  __shared__ int chs_idx[264];
  char* sm = (char*)smemf;
  const int tid = threadIdx.x;
  const int bid = blockIdx.x;

  if (bid < 2048){
    // ---------- conv-GEMM block: 256 positions (16 s) of batch b ----------
    const int b = bid >> 5, sg = bid & 31;
    // stage ch indices once
    for (int i = tid; i < 258; i += 256){
      int pl = sg*256 - 1 + i;
      chs_idx[i] = (pl >= 0 && pl < 8192) ? ch[b*8192 + pl] : -1;
    }
    // stage B weights [cc=64][k'=192] bf16 (k' = dc*64 + ce; pads zero)
    for (int i = tid; i < 6144; i += 256){
      int row = i/96, pair = i - row*96;
      int k0 = pair*2;
      int dc = k0 >> 6, ce = k0 & 63;
      float v0 = 0.f, v1 = 0.f;
      if (row < 50 && ce < 50){
        v0 = cw[row*150 + ce*3 + dc];
        if (ce + 1 < 50) v1 = cw[row*150 + (ce+1)*3 + dc];
      }
      *(u32*)(sm + WBB(row, pair*4)) = pk2(v0, v1);
    }
    __syncthreads();
    // stage ce rows [258][64] bf16 via chs_idx
    for (int i = tid; i < 8256; i += 256){
      int row = i >> 5, pair = i & 31;
      int ce0 = pair*2;
      float v0 = 0.f, v1 = 0.f;
      int ci = chs_idx[row];
      if (ci >= 0 && ce0 < 50){
        float2 f = *(const float2*)(ctab + (size_t)ci*50 + ce0);
        v0 = f.x; v1 = f.y;
      }
      *(u32*)(sm + CEB(row, pair*4)) = pk2(v0, v1);
    }
    __syncthreads();

    const int wv = tid >> 6, lane = tid & 63;
    const int lr = lane & 15, lq = lane >> 4;
    f32x4 acc[4][4];
    #pragma unroll
    for (int mt = 0; mt < 4; mt++)
      #pragma unroll
      for (int nt = 0; nt < 4; nt++) acc[mt][nt] = (f32x4){0.f,0.f,0.f,0.f};
    #pragma unroll
    for (int kk = 0; kk < 6; kk++){
      const int kp = kk*32 + lq*8;
      const int dc = kp >> 6;
      short8 bfr[4], af[4];
      #pragma unroll
      for (int nt = 0; nt < 4; nt++)
        bfr[nt] = *(const short8*)(sm + WBB(nt*16 + lr, kp*2));
      #pragma unroll
      for (int mt = 0; mt < 4; mt++){
        const int pos = (wv*4 + mt)*16 + lr;
        af[mt] = *(const short8*)(sm + CEB(pos + dc, (kp & 63)*2));
      }
      #pragma unroll
      for (int mt = 0; mt < 4; mt++)
        #pragma unroll
        for (int nt = 0; nt < 4; nt++)
          acc[mt][nt] = __builtin_amdgcn_mfma_f32_16x16x32_bf16(af[mt], bfr[nt], acc[mt][nt], 0,0,0);
    }
    // maxpool over w (the 16 rows of each m-tile) + bias + store
    #pragma unroll
    for (int mt = 0; mt < 4; mt++){
      const int s = sg*16 + wv*4 + mt;
      #pragma unroll
      for (int nt = 0; nt < 4; nt++){
        float m = fmaxf(fmaxf(acc[mt][nt][0], acc[mt][nt][1]),
                        fmaxf(acc[mt][nt][2], acc[mt][nt][3]));
        m = fmaxf(m, __shfl_xor(m, 16, 64));
        m = fmaxf(m, __shfl_xor(m, 32, 64));
        const int cc = nt*16 + lr;
        if (lq == 0 && cc < 50)
          feat[(size_t)(s*64 + b)*416 + 350 + cc] = f2bf(m + cb[cc]);
      }
    }
    return;
  }

  if (bid < 4096){
    // ---------- copy blocks: embed/tag/pad rows of feat ----------
    const int cid = bid - 2048;           // 0..2047, 16 rows each
    const int w = tid >> 6, lane = tid & 63;
    #pragma unroll
    for (int r = 0; r < 4; r++){
      const int m = cid*16 + w*4 + r;     // row = s*64+b
      const int s = m >> 6, b = m & 63;
      const int xi = X[b*512 + s];
      const int ti = tg[b*512 + s];
      u32* dst = (u32*)feat + (size_t)m*208;
      #pragma unroll
      for (int pass = 0; pass < 3; pass++){
        int word = pass*64 + lane;
        if (word < 150){
          float2 f = *(const float2*)(etab + (size_t)xi*300 + word*2);
          dst[word] = pk2(f.x, f.y);
        } else if (word < 175){
          float2 f = *(const float2*)(ttab + (size_t)ti*50 + (word-150)*2);
          dst[word] = pk2(f.x, f.y);
        } else if (word < 183){
          dst[200 + word - 175] = 0u;
        }
      }
    }
    return;
  }

  // ---------- k0 blocks ----------
  const int bx = bid - 4096;              // 0..2560
  if (bx > 512){
    const int n = bx - 513;
    const float* src = (n < 1024) ? (wihf + (size_t)n*400) : (wihb + (size_t)(n-1024)*400);
    u32* dst = (u32*)(wih + (size_t)n*416);
    if (tid < 208){
      int j = tid*2;
      u32 v = 0u;
      if (j < 400){
        float2 f = *(const float2*)(src + j);
        v = pk2(f.x, f.y);
      }
      dst[tid] = v;
    }
    return;
  }
  if (bx == 512){
    float* red = smemf;
    for (int n = tid; n < 2048; n += 256){
      bias[n] = (n < 1024) ? (bihf[n] + bhhf[n]) : (bihb[n-1024] + bhhb[n-1024]);
    }
    const int cur = tid & 15, part = tid >> 4;
    float s = 0.f;
    for (int k = part*32; k < part*32 + 32; k++) s += fcw[cur*512 + k] * wdp[k];
    red[tid] = s;
    __syncthreads();
    if (tid < 16){
      float t = 0.f;
      #pragma unroll
      for (int p = 0; p < 16; p++) t += red[p*16 + tid];
      wfc[tid] = t;
    }
    return;
  }
  {
    const int row = bx*4 + (tid >> 6);
    const int lane = tid & 63;
    const float* src = (row < 1024) ? (whhf + (size_t)row*256)
                                    : (whhb + (size_t)(row-1024)*256);
    f32x4 v = *(const f32x4*)(src + lane*4);
    float m = fmaxf(fmaxf(fabsf(v[0]), fabsf(v[1])), fmaxf(fabsf(v[2]), fabsf(v[3])));
    #pragma unroll
    for (int d = 1; d < 64; d <<= 1) m = fmaxf(m, __shfl_xor(m, d, 64));
    float inv = 127.f / (m + 1e-30f);
    u32 pack = 0;
    #pragma unroll
    for (int e = 0; e < 4; e++){
      int q = (int)rintf(v[e]*inv);
      q = q > 127 ? 127 : (q < -127 ? -127 : q);
      pack |= ((u32)(u8)(s8)q) << (8*e);
    }
    const int dir = row >> 10, n = row & 1023;
    const int g = n >> 8, j = n & 255, w2 = j >> 4, lr2 = j & 15;
    const int kk = lane >> 4, lq2 = (lane >> 2) & 3, e4 = lane & 3;
    u32* wq32 = (u32*)wq;
    wq32[dir*65536 + (((g*16 + w2)*4 + kk)*64 + lq2*16 + lr2)*4 + e4] = pack;
    if (lane == 0) sc2[row] = m * (1.f/16129.f);
  }
}
#undef CEB
#undef WBB

// ---------------- K2: gi = bf16(feat @ wih^T + bias), dbuf + LDS epilogue ----------------
__global__ __launch_bounds__(256) void k2_gemm(
    const u16* __restrict__ featp, const u16* __restrict__ wihp,
    const float* __restrict__ bias, u16* __restrict__ gi)
{
  const int m0 = blockIdx.y*128, n0 = blockIdx.x*128;
  const int tid = threadIdx.x, wv = tid>>6, lane = tid&63;
  const int lr = lane & 15, lq = lane >> 4;
  const int wm = (wv>>1)*64, wn = (wv&1)*64;
  __shared__ u16 smem2[16384];   // As[2][4096] | Bs[2][4096]; reused as C stage
  u16 (*As)[4096] = (u16(*)[4096])smem2;
  u16 (*Bs)[4096] = (u16(*)[4096])(smem2 + 8192);
  f32x4 acc[4][4];
  #pragma unroll
  for (int a=0;a<4;a++)
    #pragma unroll
    for (int c=0;c<4;c++) acc[a][c] = (f32x4){0.f,0.f,0.f,0.f};

  #define K2_STAGE(BUF, K0) { \
    _Pragma("unroll") \
    for (int i = 0; i < 2; i++){ \
      int c = i*4 + wv; \
      gld_lds16(featp + (size_t)(m0 + c*16 + (lane>>2))*416 + (K0) + (lane&3)*8, &As[BUF][c*512]); \
      gld_lds16(wihp  + (size_t)(n0 + c*16 + (lane>>2))*416 + (K0) + (lane&3)*8, &Bs[BUF][c*512]); \
    } }

  K2_STAGE(0, 0);
  __syncthreads();
  int buf = 0;
  for (int ki = 0; ki < 13; ki++){
    if (ki < 12) K2_STAGE(buf^1, (ki+1)*32);
    short8 af[4], bfr[4];
    #pragma unroll
    for (int mt=0; mt<4; mt++) af[mt]  = *(const short8*)(&As[buf][0] + (wm + mt*16 + lr)*32 + lq*8);
    #pragma unroll
    for (int nt=0; nt<4; nt++) bfr[nt] = *(const short8*)(&Bs[buf][0] + (wn + nt*16 + lr)*32 + lq*8);
    #pragma unroll
    for (int mt=0; mt<4; mt++)
      #pragma unroll
      for (int nt=0; nt<4; nt++)
        acc[mt][nt] = __builtin_amdgcn_mfma_f32_16x16x32_bf16(af[mt], bfr[nt], acc[mt][nt], 0,0,0);
    __syncthreads();
    buf ^= 1;
  }
  #undef K2_STAGE
  // epilogue: stage C (bias fused, bf16) in LDS [128][128] XOR-swizzled,
  // then fully-coalesced 16B stores covering ALL 128 columns per row.
  #pragma unroll
  for (int nt=0; nt<4; nt++){
    const int col = wn + nt*16 + lr;
    const float bv = bias[n0 + col];
    #pragma unroll
    for (int mt=0; mt<4; mt++)
      #pragma unroll
      for (int r=0; r<4; r++){
        const int row = wm + mt*16 + lq*4 + r;
        smem2[row*128 + (col ^ ((row & 7) << 4))] = f2bf(acc[mt][nt][r] + bv);
      }
  }
  __syncthreads();
  {
    const int row = tid >> 1, half = tid & 1;
    u16* dst = gi + (size_t)(m0 + row)*2048 + n0;
    #pragma unroll
    for (int c = 0; c < 8; c++){
      const int c8 = half*8 + c;   // [0,16): 16 chunks x 8 u16 = 128 cols
      short8 v = *(const short8*)&smem2[row*128 + ((c8*8) ^ ((row & 7) << 4))];
      *(short8*)(dst + c8*8) = v;
    }
  }
}

// ---------------- K3: recurrent BiLSTM, 64 blocks x 512 thr, all-VGPR weights ----------------
__global__ __launch_bounds__(512, 2) void k3_lstm(
    const s8* __restrict__ wq, const float* __restrict__ sc2,
    const u16* __restrict__ gi, u16* __restrict__ hcat)
{
  const int dir = blockIdx.x >> 5;
  const int bb  = (blockIdx.x & 31) * 2;
  const int tid = threadIdx.x;
  const int w = tid >> 6, lane = tid & 63;
  const int lr = lane & 15, lq = lane >> 4;
  const int cb = tid >> 8, cj = tid & 255;

  __shared__ s8 Hs[2][4096];
  __shared__ float xbuf[2048];

  const s8* wqd = wq + dir*262144;
  int4v bq[2][4][4];
  #pragma unroll
  for (int sl = 0; sl < 2; sl++)
    #pragma unroll
    for (int g = 0; g < 4; g++)
      #pragma unroll
      for (int kk = 0; kk < 4; kk++)
        bq[sl][g][kk] = *(const int4v*)(wqd + (((((g*16 + 2*w + sl)*4 + kk)*64) + lane) << 4));

  float scl[4];
  #pragma unroll
  for (int g = 0; g < 4; g++) scl[g] = sc2[dir*1024 + g*256 + cj];

  *(uint2*)&Hs[0][tid*8] = (uint2){0u,0u};
  *(uint2*)&Hs[1][tid*8] = (uint2){0u,0u};

  float cst = 0.f;
  const ptrdiff_t dstep = dir ? -(ptrdiff_t)131072 : (ptrdiff_t)131072;
  const u16* g0 = gi + (size_t)((dir ? 511 : 0)*64 + bb + cb)*2048 + dir*1024 + cj;
  u32 gcur[4], gn1[4], gn2[4];
  #pragma unroll
  for (int g = 0; g < 4; g++) gcur[g] = g0[g*256];
  const u16* g1 = g0 + dstep;
  #pragma unroll
  for (int g = 0; g < 4; g++) gn1[g] = g1[g*256];
  const u16* gpref = g1;
  __syncthreads();

  #pragma unroll 1
  for (int t = 0; t < 512; t++){
    const int s = dir ? (511 - t) : t;
    if (t + 2 < 512) gpref += dstep;
    #pragma unroll
    for (int g = 0; g < 4; g++) gn2[g] = gpref[g*256];
    const s8* hb = Hs[t & 1];
    int4v aq[4];
    #pragma unroll
    for (int kk = 0; kk < 4; kk++)
      aq[kk] = *(const int4v*)(hb + lr*256 + ((kk*64 + lq*16) ^ (lr << 4)));
    int4v acc[2][4];
    #pragma unroll
    for (int sl = 0; sl < 2; sl++)
      #pragma unroll
      for (int g = 0; g < 4; g++) acc[sl][g] = (int4v){0,0,0,0};
    __builtin_amdgcn_s_setprio(1);
    #pragma unroll
    for (int kk = 0; kk < 4; kk++)
      #pragma unroll
      for (int sl = 0; sl < 2; sl++)
        #pragma unroll
        for (int g = 0; g < 4; g++)
          acc[sl][g] = __builtin_amdgcn_mfma_i32_16x16x64_i8(aq[kk], bq[sl][g][kk], acc[sl][g], 0,0,0);
    __builtin_amdgcn_s_setprio(0);
    if (lq == 0){
      #pragma unroll
      for (int sl = 0; sl < 2; sl++){
        const int j = (2*w + sl)*16 + lr;
        #pragma unroll
        for (int r = 0; r < 2; r++){
          f32x4 v = (f32x4){(float)acc[sl][0][r], (float)acc[sl][1][r],
                            (float)acc[sl][2][r], (float)acc[sl][3][r]};
          *(f32x4*)&xbuf[(r*256 + j)*4] = v;
        }
      }
    }
    bar_l();
    f32x4 p = *(const f32x4*)&xbuf[tid*4];
    float g4[4];
    #pragma unroll
    for (int g = 0; g < 4; g++) g4[g] = bf2f((u16)gcur[g]) + p[g]*scl[g];
    float iv = sigf(g4[0]), fv = sigf(g4[1]);
    float gg = tanh_f(g4[2]), ov = sigf(g4[3]);
    float c = fv*cst + iv*gg;
    cst = c;
    float h = ov * tanh_f(c);
    hcat[(size_t)(s*64 + bb + cb)*512 + dir*256 + cj] = f2bf(h);
    Hs[(t + 1) & 1][cb*256 + (cj ^ (cb << 4))] = (s8)(int)rintf(h * 127.f);
    #pragma unroll
    for (int g = 0; g < 4; g++){ gcur[g] = gn1[g]; gn1[g] = gn2[g]; }
    bar_l();
  }
}

// ---------------- K4: P = Hcat @ fc_w^T + fc_b + lm*wfc  [32768 x 16] fp32 ----------------
__global__ __launch_bounds__(256) void k4_fc(
    const u16* __restrict__ hcat, const float* __restrict__ fcw, const float* __restrict__ fcb,
    const float* __restrict__ lmp, const float* __restrict__ wfc, float* __restrict__ Pout)
{
  const int wv = threadIdx.x >> 6, lane = threadIdx.x & 63;
  const int lr = lane & 15, lq = lane >> 4;
  const int mt = blockIdx.x*4 + wv;
  short8 bfr[16];
  #pragma unroll
  for (int kk = 0; kk < 16; kk++){
    const float* wr = fcw + (size_t)lr*512 + kk*32 + lq*8;
    f32x4 w0 = *(const f32x4*)wr;
    f32x4 w1 = *(const f32x4*)(wr + 4);
    short8 sv;
    #pragma unroll
    for (int e = 0; e < 4; e++){ sv[e] = (short)f2bf(w0[e]); sv[4+e] = (short)f2bf(w1[e]); }
    bfr[kk] = sv;
  }
  f32x4 acc = (f32x4){0.f,0.f,0.f,0.f};
  #pragma unroll
  for (int kk = 0; kk < 16; kk++){
    short8 af = *(const short8*)(hcat + (size_t)(mt*16 + lr)*512 + kk*32 + lq*8);
    acc = __builtin_amdgcn_mfma_f32_16x16x32_bf16(af, bfr[kk], acc, 0,0,0);
  }
  const int cur = lr;
  float fb = fcb[cur];
  float wf = wfc[cur];
  #pragma unroll
  for (int r = 0; r < 4; r++){
    int m = mt*16 + lq*4 + r;
    int b = m & 63, s = m >> 6;
    float lmv = lmp[b*512 + s];
    Pout[(size_t)m*16 + cur] = acc[r] + fb + lmv*wf;
  }
}

// ---------------- K5: Viterbi — shuffle-free (replicated delta + readlane) ----------------
__global__ __launch_bounds__(64) void k5_vit(
    const float* __restrict__ Pg, const float* __restrict__ Am,
    float* __restrict__ dout, float* __restrict__ dl, u8* __restrict__ psi)
{
  const int b = blockIdx.x, lane = threadIdx.x;
  const int cur = lane & 15;
  float Ar[16];
  #pragma unroll
  for (int p = 0; p < 16; p++) Ar[p] = Am[p*16 + cur];
  float dreg[16];
  {
    float v0 = Pg[(size_t)b*16 + cur];
    if (lane < 16) dl[(size_t)b*16 + cur] = v0;
    #pragma unroll
    for (int c = 0; c < 16; c++) dreg[c] = rdlane_f(v0, c);
  }

#define FSTEP(X, S) { \
    float v_[16]; \
    _Pragma("unroll") \
    for (int p = 0; p < 16; p++) v_[p] = dreg[p] + Ar[p]; \
    float m1[8]; int i1[8]; \
    _Pragma("unroll") \
    for (int k = 0; k < 8; k++){ bool c_ = v_[2*k] >= v_[2*k+1]; \
      m1[k] = c_ ? v_[2*k] : v_[2*k+1]; i1[k] = c_ ? 2*k : 2*k+1; } \
    float m2[4]; int i2[4]; \
    _Pragma("unroll") \
    for (int k = 0; k < 4; k++){ bool c_ = m1[2*k] >= m1[2*k+1]; \
      m2[k] = c_ ? m1[2*k] : m1[2*k+1]; i2[k] = c_ ? i1[2*k] : i1[2*k+1]; } \
    float m3[2]; int i3[2]; \
    _Pragma("unroll") \
    for (int k = 0; k < 2; k++){ bool c_ = m2[2*k] >= m2[2*k+1]; \
      m3[k] = c_ ? m2[2*k] : m2[2*k+1]; i3[k] = c_ ? i2[2*k] : i2[2*k+1]; } \
    bool cf_ = m3[0] >= m3[1]; \
    float best = (cf_ ? m3[0] : m3[1]) + (X); \
    int bi = cf_ ? i3[0] : i3[1]; \
    if (lane < 16){ \
      dl[(size_t)((S)*64 + b)*16 + cur] = best; \
      psi[(size_t)((S)*64 + b)*16 + cur] = (u8)bi; \
    } \
    _Pragma("unroll") \
    for (int c = 0; c < 16; c++) dreg[c] = rdlane_f(best, c); \
  }

  float x0 = Pg[(size_t)(1*64 + b)*16 + cur];
  float x1 = Pg[(size_t)(2*64 + b)*16 + cur];
  float x2 = Pg[(size_t)(3*64 + b)*16 + cur];
  float x3 = Pg[(size_t)(4*64 + b)*16 + cur];
  for (int s = 1; s < 512; s += 4){
    FSTEP(x0, s);
    if (s + 4 < 512) x0 = Pg[(size_t)((s+4)*64 + b)*16 + cur];
    if (s + 1 < 512) FSTEP(x1, s+1);
    if (s + 5 < 512) x1 = Pg[(size_t)((s+5)*64 + b)*16 + cur];
    if (s + 2 < 512) FSTEP(x2, s+2);
    if (s + 6 < 512) x2 = Pg[(size_t)((s+6)*64 + b)*16 + cur];
    if (s + 3 < 512) FSTEP(x3, s+3);
    if (s + 7 < 512) x3 = Pg[(size_t)((s+7)*64 + b)*16 + cur];
  }
#undef FSTEP

  float bv = dreg[0]; int bix = 0;
  #pragma unroll
  for (int c = 1; c < 16; c++){ if (dreg[c] > bv){ bv = dreg[c]; bix = c; } }
  int tag = bix;
  float score = bv;
  if (lane == 0) dout[b*512 + 511] = (float)tag;

#define BSTEP(PV, DV, T) { \
    int prev = __builtin_amdgcn_readlane((PV), tag); \
    score += rdlane_f((DV), prev); \
    if (lane == 0) dout[b*512 + (T)] = (float)prev; \
    tag = prev; }

  int   p0 = 0, p1 = 0, p2 = 0, p3 = 0;
  float d0 = 0.f, d1 = 0.f, d2 = 0.f, d3 = 0.f;
  if (lane < 16){
    p0 = psi[(size_t)(511*64 + b)*16 + lane]; d0 = dl[(size_t)(510*64 + b)*16 + lane];
    p1 = psi[(size_t)(510*64 + b)*16 + lane]; d1 = dl[(size_t)(509*64 + b)*16 + lane];
    p2 = psi[(size_t)(509*64 + b)*16 + lane]; d2 = dl[(size_t)(508*64 + b)*16 + lane];
    p3 = psi[(size_t)(508*64 + b)*16 + lane]; d3 = dl[(size_t)(507*64 + b)*16 + lane];
  }
  for (int t = 510; t >= 0; t -= 4){
    BSTEP(p0, d0, t);
    if (t - 4 >= 0 && lane < 16){
      p0 = psi[(size_t)((t-3)*64 + b)*16 + lane]; d0 = dl[(size_t)((t-4)*64 + b)*16 + lane];
    }
    if (t - 1 >= 0) BSTEP(p1, d1, t-1);
    if (t - 5 >= 0 && lane < 16){
      p1 = psi[(size_t)((t-4)*64 + b)*16 + lane]; d1 = dl[(size_t)((t-5)*64 + b)*16 + lane];
    }
    if (t - 2 >= 0) BSTEP(p2, d2, t-2);
    if (t - 6 >= 0 && lane < 16){
      p2 = psi[(size_t)((t-5)*64 + b)*16 + lane]; d2 = dl[(size_t)((t-6)*64 + b)*16 + lane];
    }
    if (t - 3 >= 0) BSTEP(p3, d3, t-3);
    if (t - 7 >= 0 && lane < 16){
      p3 = psi[(size_t)((t-6)*64 + b)*16 + lane]; d3 = dl[(size_t)((t-7)*64 + b)*16 + lane];
    }
  }
#undef BSTEP
  if (lane == 0) dout[32768 + b] = score;
}

// ---------------- launcher ----------------
extern "C" void kernel_launch(void* const* d_in, const int* in_sizes, int n_in,
                              void* d_out, int out_size, void* d_ws, size_t ws_size,
                              hipStream_t stream)
{
  (void)in_sizes; (void)n_in; (void)out_size;
  if (ws_size < REQUIRED) return;

  const int*   X    = (const int*)d_in[0];
  const float* lm   = (const float*)d_in[1];
  const int*   tg   = (const int*)d_in[2];
  const int*   ch   = (const int*)d_in[3];
  const float* etab = (const float*)d_in[4];
  const float* ttab = (const float*)d_in[5];
  const float* ctab = (const float*)d_in[6];
  const float* cw   = (const float*)d_in[7];
  const float* cb   = (const float*)d_in[8];
  const float* wihf = (const float*)d_in[9];
  const float* whhf = (const float*)d_in[10];
  const float* bihf = (const float*)d_in[11];
  const float* bhhf = (const float*)d_in[12];
  const float* wihb = (const float*)d_in[13];
  const float* whhb = (const float*)d_in[14];
  const float* bihb = (const float*)d_in[15];
  const float* bhhb = (const float*)d_in[16];
  const float* fcw  = (const float*)d_in[17];
  const float* fcb  = (const float*)d_in[18];
  const float* Am   = (const float*)d_in[19];
  const float* wdp  = (const float*)d_in[20];

  char* ws = (char*)d_ws;
  u16*   gi   = (u16*)(ws + OFF_GI);
  u16*   feat = (u16*)(ws + OFF_B);
  u16*   hcat = (u16*)(ws + OFF_B);
  u16*   wih  = (u16*)(ws + OFF_WIH);
  s8*    wq   = (s8*)(ws + OFF_WQ);
  float* sc2  = (float*)(ws + OFF_SC);
  float* Pg   = (float*)(ws + OFF_P);
  float* dlt  = (float*)(ws + OFF_DL);
  u8*    psi  = (u8*)(ws + OFF_PSI);
  float* bias = (float*)(ws + OFF_BIAS);
  float* wfc  = (float*)(ws + OFF_WFC);
  float* dout = (float*)d_out;

  k01_fused<<<6657, 256, 0, stream>>>(X, tg, ch, etab, ttab, ctab, cw, cb, feat,
                                      whhf, whhb, wq, sc2,
                                      bihf, bhhf, bihb, bhhb, fcw, wdp, bias, wfc,
                                      wihf, wihb, wih);
  k2_gemm<<<dim3(16, 256), 256, 0, stream>>>(feat, wih, bias, gi);
  k3_lstm<<<64, 512, 0, stream>>>(wq, sc2, gi, hcat);
  k4_fc<<<512, 256, 0, stream>>>(hcat, fcw, fcb, lm, wfc, Pg);
  k5_vit<<<64, 64, 0, stream>>>(Pg, Am, dout, dlt, psi);
}